// Round 8
// baseline (226.237 us; speedup 1.0000x reference)
//
#include <hip/hip_runtime.h>
#include <hip/hip_fp16.h>
#include <math.h>

#define N_NODES 50000
#define N_EDGES 800000
#define DIM 128
#define NHEADS 8
#define LN_EPS 1e-5f
#define LEAKY 0.2f
#define NBINS 512
#define NPB 98     // nodes per bin; 512*98 = 50176 >= N_NODES
#define NCHUNK 256 // edge chunks for counting sort
#define EPC 3125   // edges per chunk; 256*3125 = 800000 exactly
#define CAP 2560   // max edges per bin held in LDS (mean 1568, sigma ~40)

typedef _Float16 half8 __attribute__((ext_vector_type(8)));
typedef float floatx4 __attribute__((ext_vector_type(4)));

// ---------------- pack/unpack (P, deter) as half2 in one int ----------------
__device__ __forceinline__ int pack_pd(float p, float dt) {
    __half2 h = __floats2half2_rn(p, dt);
    int r; __builtin_memcpy(&r, &h, 4); return r;
}
__device__ __forceinline__ float2 unpack_pd(int v) {
    __half2 h; __builtin_memcpy(&h, &v, 4);
    return __half22float2(h);   // .x = P, .y = deter
}

// -- K1 (fused): blocks 0..127 -> Wch/Wcat[0:128]/bsum; 128..135 -> attn rows;
//    blocks 136..391 -> per-chunk per-bin histograms (counting sort phase 1).
__global__ __launch_bounds__(256) void k_init(
    const float* __restrict__ W1, const float* __restrict__ W2,
    const float* __restrict__ W3, const float* __restrict__ W4,
    const float* __restrict__ Wout, const float* __restrict__ Wres,
    const float* __restrict__ Wv, const float* __restrict__ bout,
    const float* __restrict__ bres, const int* __restrict__ ei,
    __half* __restrict__ Wch, __half* __restrict__ Wcat,
    float* __restrict__ bsum, float* __restrict__ c,
    int* __restrict__ cnt) {
    __shared__ float red[DIM];
    __shared__ int hh[NBINS];
    int b = blockIdx.x;
    int t = threadIdx.x;
    if (b < 128) {
        int d = b;
        float v = (t < 128) ? Wout[d * 128 + t] : Wres[d * 128 + (t - 128)];
        Wch[(size_t)d * 256 + t] = __float2half_rn(v);
        if (t < 128) Wcat[(size_t)d * DIM + t] = __float2half_rn(Wv[d * 128 + t]);
        if (d == 0 && t < 128) bsum[t] = bout[t] + bres[t];
    } else if (b < 136) {
        int h = b - 128;          // 0..7
        if (t < 128) {
            int k = t;
            float a1 = 0.f, a2 = 0.f;
            for (int d = 0; d < DIM; ++d) {
                float w4 = W4[h * DIM + d];
                a1 += w4 * W1[d * DIM + k];
                a2 += w4 * W2[d * DIM + k];
            }
            Wcat[(size_t)(128 + h) * DIM + k] = __float2half_rn(a1);
            Wcat[(size_t)(136 + h) * DIM + k] = __float2half_rn(a2);
        }
        if (t < 128) red[t] = W4[h * DIM + t] * W3[t];
        __syncthreads();
        if (t == 0) {
            float s = 0.f;
            for (int i = 0; i < DIM; ++i) s += red[i];
            c[h] = s;
        }
    } else {
        int ch = b - 136;         // chunk 0..255
        for (int i = t; i < NBINS; i += 256) hh[i] = 0;
        __syncthreads();
        int e0 = ch * EPC;
        for (int i = t; i < EPC; i += 256) {
            int dst = ei[N_EDGES + e0 + i];
            atomicAdd(&hh[dst / NPB], 1);      // LDS atomic — block-local
        }
        __syncthreads();
        // layout [chunk][bin] so k_place's reload is coalesced
        for (int i = t; i < NBINS; i += 256)
            cnt[(size_t)ch * NBINS + i] = hh[i];
    }
}

// -- K2: MFMA  Y = H @ Wcat^T  (M=N_NODES, N=144, K=128, fp16 in / fp32 acc) -
//   cols 0..127 -> Vh (fp16), cols 128..135 -> A1, 136..143 -> A2 (fp32)
//   side effect: Xh[:,128:256] = fp16(H)  (converted A-fragments)
__global__ __launch_bounds__(64) void k_node_mfma(
    const float* __restrict__ H, const __half* __restrict__ Wcat_,
    __half* __restrict__ Vh, __half* __restrict__ Xh,
    float* __restrict__ A1, float* __restrict__ A2) {
    const _Float16* Wcat = reinterpret_cast<const _Float16*>(Wcat_);
    int lane = threadIdx.x;          // 0..63
    int m = lane & 15, q = lane >> 4;
    int n0 = blockIdx.x * 32;
    floatx4 z = {0.f, 0.f, 0.f, 0.f};
    floatx4 acc[2][9];
    #pragma unroll
    for (int t = 0; t < 2; ++t)
        #pragma unroll
        for (int j = 0; j < 9; ++j) acc[t][j] = z;
    int r0 = n0 + m;        if (r0 >= N_NODES) r0 = N_NODES - 1;
    int r1 = n0 + 16 + m;   if (r1 >= N_NODES) r1 = N_NODES - 1;
    const float* H0 = H + (size_t)r0 * DIM + q * 8;
    const float* H1 = H + (size_t)r1 * DIM + q * 8;
    _Float16* Xw0 = reinterpret_cast<_Float16*>(Xh) + (size_t)r0 * 256 + 128 + q * 8;
    _Float16* Xw1 = reinterpret_cast<_Float16*>(Xh) + (size_t)r1 * 256 + 128 + q * 8;
    const _Float16* Wb = Wcat + (size_t)m * DIM + q * 8;
    #pragma unroll
    for (int ks = 0; ks < 4; ++ks) {
        float4 fa = *reinterpret_cast<const float4*>(H0 + ks * 32);
        float4 fb = *reinterpret_cast<const float4*>(H0 + ks * 32 + 4);
        float4 ga = *reinterpret_cast<const float4*>(H1 + ks * 32);
        float4 gb = *reinterpret_cast<const float4*>(H1 + ks * 32 + 4);
        half8 a0, a1v;
        a0[0] = (_Float16)fa.x; a0[1] = (_Float16)fa.y;
        a0[2] = (_Float16)fa.z; a0[3] = (_Float16)fa.w;
        a0[4] = (_Float16)fb.x; a0[5] = (_Float16)fb.y;
        a0[6] = (_Float16)fb.z; a0[7] = (_Float16)fb.w;
        a1v[0] = (_Float16)ga.x; a1v[1] = (_Float16)ga.y;
        a1v[2] = (_Float16)ga.z; a1v[3] = (_Float16)ga.w;
        a1v[4] = (_Float16)gb.x; a1v[5] = (_Float16)gb.y;
        a1v[6] = (_Float16)gb.z; a1v[7] = (_Float16)gb.w;
        *reinterpret_cast<half8*>(Xw0 + ks * 32) = a0;
        *reinterpret_cast<half8*>(Xw1 + ks * 32) = a1v;
        #pragma unroll
        for (int j = 0; j < 9; ++j) {
            half8 b = *reinterpret_cast<const half8*>(Wb + (size_t)j * 16 * DIM + ks * 32);
            acc[0][j] = __builtin_amdgcn_mfma_f32_16x16x32_f16(a0, b, acc[0][j], 0, 0, 0);
            acc[1][j] = __builtin_amdgcn_mfma_f32_16x16x32_f16(a1v, b, acc[1][j], 0, 0, 0);
        }
    }
    // C/D layout: col = m, row = q*4 + reg (within 16-row tile)
    #pragma unroll
    for (int t = 0; t < 2; ++t) {
        #pragma unroll
        for (int reg = 0; reg < 4; ++reg) {
            int n = n0 + t * 16 + q * 4 + reg;
            if (n < N_NODES) {
                #pragma unroll
                for (int j = 0; j < 8; ++j)
                    Vh[(size_t)n * DIM + j * 16 + m] = __float2half_rn(acc[t][j][reg]);
                float av = acc[t][8][reg];
                if (m < 8) A1[(size_t)n * NHEADS + m] = av;
                else       A2[(size_t)n * NHEADS + (m - 8)] = av;
            }
        }
    }
}

// ---------------- K5b: per-bin scan over chunks (relative); bin totals ------
__global__ __launch_bounds__(NCHUNK) void k_scanchunk(
    const int* __restrict__ cnt, int* __restrict__ ofs,
    int* __restrict__ binTot) {
    __shared__ int sh[NCHUNK];
    int b = blockIdx.x, t = threadIdx.x;
    int v = cnt[(size_t)t * NBINS + b];
    sh[t] = v;
    __syncthreads();
    #pragma unroll
    for (int off = 1; off < NCHUNK; off <<= 1) {
        int u = (t >= off) ? sh[t - off] : 0;
        __syncthreads();
        sh[t] += u;
        __syncthreads();
    }
    ofs[(size_t)t * NBINS + b] = sh[t] - v;   // chunk-exclusive, bin-relative
    if (t == NCHUNK - 1) binTot[b] = sh[t];
}

// -- in-block 512-wide inclusive scan of binTot (2 elems/thread, 256 thr) ----
__device__ __forceinline__ void scan512x2(const int* __restrict__ binTot,
                                          int* sc, int t) {
    sc[t] = binTot[t];
    sc[t + 256] = binTot[t + 256];
    __syncthreads();
    #pragma unroll
    for (int off = 1; off < 512; off <<= 1) {
        int a = (t >= off) ? sc[t - off] : 0;
        int b = (t + 256 >= off) ? sc[t + 256 - off] : 0;
        __syncthreads();
        sc[t] += a;
        sc[t + 256] += b;
        __syncthreads();
    }
}

// ---------------- K5d: place records into bin regions (LDS cursors) --------
// Computes bin bases from binTot in-block.
__global__ __launch_bounds__(256) void k_place(
    const int* __restrict__ ei, const float* __restrict__ P,
    const float* __restrict__ deter, const int* __restrict__ ofs,
    const int* __restrict__ binTot, int2* __restrict__ rec_tmp) {
    __shared__ int sc[NBINS];
    __shared__ int cur[NBINS];
    int t = threadIdx.x;
    scan512x2(binTot, sc, t);
    // cur[i] = chunk-relative ofs + exclusive bin base
    cur[t]       = ofs[(size_t)blockIdx.x * NBINS + t]       + sc[t]       - binTot[t];
    cur[t + 256] = ofs[(size_t)blockIdx.x * NBINS + t + 256] + sc[t + 256] - binTot[t + 256];
    __syncthreads();
    int e0 = blockIdx.x * EPC;
    for (int i = t; i < EPC; i += 256) {
        int e = e0 + i;
        int src = ei[e];
        int dst = ei[N_EDGES + e];
        int pos = atomicAdd(&cur[dst / NPB], 1);   // LDS atomic
        rec_tmp[pos] = make_int2((dst << 16) | src, pack_pd(P[e], deter[e]));
    }
}

// ---- K5e (fused): per-bin CSR build + edge exp + aggregation, all in LDS ---
// Bin b's scatter output is exactly the edge set its 98 nodes aggregate, so
// records (src + half8 exp-weights) go to LDS, never to global. After one
// barrier, the block's 8 waves aggregate straight from LDS (V gather global).
__global__ __launch_bounds__(512) void k_rebin_agg(
    const int* __restrict__ binTot, const int2* __restrict__ rec_tmp,
    const float* __restrict__ A1, const float* __restrict__ A2,
    const float* __restrict__ cvec, const __half2* __restrict__ Vh2,
    __half* __restrict__ Xh) {
    __shared__ int sc[NBINS];
    __shared__ int cnt_l[NPB];   // exclusive global starts per node
    __shared__ int cur_l[NPB];   // atomic cursors -> node ends after scatter
    __shared__ float cs[NHEADS];
    __shared__ int   wsrc[CAP];  // src per edge (bin-local order)
    __shared__ half8 wl[CAP];    // exp-weights per edge
    int b = blockIdx.x, t = threadIdx.x;
    // 512-wide inclusive scan of binTot (1 elem/thread)
    sc[t] = binTot[t];
    __syncthreads();
    #pragma unroll
    for (int off = 1; off < NBINS; off <<= 1) {
        int u = (t >= off) ? sc[t - off] : 0;
        __syncthreads();
        sc[t] += u;
        __syncthreads();
    }
    if (t < NHEADS) cs[t] = cvec[t];
    int e = sc[b];               // inclusive sum = end of bin b
    int s = e - binTot[b];       // exclusive = start of bin b
    int n0 = b * NPB;
    int nEdge = e - s;
    int d = t & 63;
    int wv = t >> 6;             // wave 0..7
    int h = d >> 3;
    if (nEdge <= CAP) {
        for (int i = t; i < NPB; i += 512) cnt_l[i] = 0;
        __syncthreads();
        for (int i = s + t; i < e; i += 512) {
            int dst = ((unsigned)rec_tmp[i].x) >> 16;
            atomicAdd(&cnt_l[dst - n0], 1);
        }
        __syncthreads();
        if (t == 0) {   // tiny serial scan over 98 entries
            int acc = s;
            for (int i = 0; i < NPB; ++i) {
                int c = cnt_l[i];
                cnt_l[i] = acc;
                cur_l[i] = acc;
                acc += c;
            }
        }
        __syncthreads();
        // scatter into LDS + fused exp(leaky(logit) - 4)
        for (int i = s + t; i < e; i += 512) {
            int2 r = rec_tmp[i];
            int dst = ((unsigned)r.x) >> 16;
            int src = r.x & 0xFFFF;
            float2 pd = unpack_pd(r.y);
            int pos = atomicAdd(&cur_l[dst - n0], 1);   // LDS atomic
            int li = pos - s;
            wsrc[li] = src;
            float4 a1lo = *reinterpret_cast<const float4*>(A1 + (size_t)dst * NHEADS);
            float4 a1hi = *reinterpret_cast<const float4*>(A1 + (size_t)dst * NHEADS + 4);
            float4 a2lo = *reinterpret_cast<const float4*>(A2 + (size_t)src * NHEADS);
            float4 a2hi = *reinterpret_cast<const float4*>(A2 + (size_t)src * NHEADS + 4);
            float a1v[8] = {a1lo.x, a1lo.y, a1lo.z, a1lo.w, a1hi.x, a1hi.y, a1hi.z, a1hi.w};
            float a2v[8] = {a2lo.x, a2lo.y, a2lo.z, a2lo.w, a2hi.x, a2hi.y, a2hi.z, a2hi.w};
            half8 o;
            #pragma unroll
            for (int hh = 0; hh < NHEADS; ++hh) {
                float l = a1v[hh] + a2v[hh] + pd.x * cs[hh] + pd.y;
                l = (l >= 0.f) ? l : LEAKY * l;
                o[hh] = (_Float16)__expf(l - 4.0f);
            }
            wl[li] = o;
        }
        __syncthreads();
        // aggregation: wave wv handles nodes wv, wv+8, ... of this bin
        for (int ni = wv; ni < NPB; ni += 8) {
            int n = n0 + ni;
            if (n >= N_NODES) break;
            int st = cnt_l[ni] - s;
            int en = cur_l[ni] - s;
            float sum = 0.f, ax = 0.f, ay = 0.f;
            int j = st;
            for (; j + 8 <= en; j += 8) {
                int sv[8];
                float wv8[8];
                __half2 vv[8];
                #pragma unroll
                for (int k = 0; k < 8; ++k) sv[k] = wsrc[j + k];
                #pragma unroll
                for (int k = 0; k < 8; ++k) wv8[k] = (float)wl[j + k][h];
                #pragma unroll
                for (int k = 0; k < 8; ++k) vv[k] = Vh2[(size_t)sv[k] * (DIM / 2) + d];
                #pragma unroll
                for (int k = 0; k < 8; ++k) {
                    sum += wv8[k];
                    float2 f = __half22float2(vv[k]);
                    ax += wv8[k] * f.x;
                    ay += wv8[k] * f.y;
                }
            }
            for (; j < en; ++j) {
                int src = wsrc[j];
                float wvv = (float)wl[j][h];
                sum += wvv;
                float2 vf = __half22float2(Vh2[(size_t)src * (DIM / 2) + d]);
                ax += wvv * vf.x;
                ay += wvv * vf.y;
            }
            float inv = 1.f / (sum + 1e-12f);
            __half2 o = __floats2half2_rn(ax * inv, ay * inv);
            *reinterpret_cast<__half2*>(Xh + (size_t)n * 256 + 2 * d) = o;
        }
    } else {
        // robust fallback (block-uniform branch; statistically never taken):
        // direct filter-aggregate from global rec_tmp, exp recomputed per lane
        __syncthreads();
        for (int ni = wv; ni < NPB; ni += 8) {
            int n = n0 + ni;
            if (n >= N_NODES) break;
            float a1 = A1[(size_t)n * NHEADS + h];
            float sum = 0.f, ax = 0.f, ay = 0.f;
            for (int i = s; i < e; ++i) {
                int2 r = rec_tmp[i];
                int dst = ((unsigned)r.x) >> 16;
                if (dst != n) continue;
                int src = r.x & 0xFFFF;
                float2 pd = unpack_pd(r.y);
                float a2 = A2[(size_t)src * NHEADS + h];
                float l = a1 + a2 + pd.x * cs[h] + pd.y;
                l = (l >= 0.f) ? l : LEAKY * l;
                float ev = __expf(l - 4.0f);
                sum += ev;
                float2 vf = __half22float2(Vh2[(size_t)src * (DIM / 2) + d]);
                ax += ev * vf.x;
                ay += ev * vf.y;
            }
            float inv = 1.f / (sum + 1e-12f);
            __half2 o = __floats2half2_rn(ax * inv, ay * inv);
            *reinterpret_cast<__half2*>(Xh + (size_t)n * 256 + 2 * d) = o;
        }
    }
}

// -- K7: out = Xh(N,256) @ Wch(128,256)^T + bsum, LayerNorm — MFMA -----------
__global__ __launch_bounds__(64) void k_out_mfma(
    const __half* __restrict__ Xh_, const __half* __restrict__ Wch_,
    const float* __restrict__ bsum, const float* __restrict__ ln_g,
    const float* __restrict__ ln_b, float* __restrict__ out) {
    const _Float16* Xh = reinterpret_cast<const _Float16*>(Xh_);
    const _Float16* Wch = reinterpret_cast<const _Float16*>(Wch_);
    int lane = threadIdx.x;          // 0..63
    int m = lane & 15, q = lane >> 4;
    int n0 = blockIdx.x * 32;
    floatx4 z = {0.f, 0.f, 0.f, 0.f};
    floatx4 acc[2][8];
    #pragma unroll
    for (int t = 0; t < 2; ++t)
        #pragma unroll
        for (int j = 0; j < 8; ++j) acc[t][j] = z;
    int r0 = n0 + m;        if (r0 >= N_NODES) r0 = N_NODES - 1;
    int r1 = n0 + 16 + m;   if (r1 >= N_NODES) r1 = N_NODES - 1;
    const _Float16* X0 = Xh + (size_t)r0 * 256 + q * 8;
    const _Float16* X1 = Xh + (size_t)r1 * 256 + q * 8;
    const _Float16* Wb = Wch + (size_t)m * 256 + q * 8;
    #pragma unroll
    for (int ks = 0; ks < 8; ++ks) {
        half8 a0 = *reinterpret_cast<const half8*>(X0 + ks * 32);
        half8 a1 = *reinterpret_cast<const half8*>(X1 + ks * 32);
        #pragma unroll
        for (int j = 0; j < 8; ++j) {
            half8 b = *reinterpret_cast<const half8*>(Wb + (size_t)j * 16 * 256 + ks * 32);
            acc[0][j] = __builtin_amdgcn_mfma_f32_16x16x32_f16(a0, b, acc[0][j], 0, 0, 0);
            acc[1][j] = __builtin_amdgcn_mfma_f32_16x16x32_f16(a1, b, acc[1][j], 0, 0, 0);
        }
    }
    float bsv[8], gv[8], bv[8];
    #pragma unroll
    for (int j = 0; j < 8; ++j) {
        bsv[j] = bsum[j * 16 + m];
        gv[j]  = ln_g[j * 16 + m];
        bv[j]  = ln_b[j * 16 + m];
    }
    #pragma unroll
    for (int t = 0; t < 2; ++t) {
        #pragma unroll
        for (int reg = 0; reg < 4; ++reg) {
            float v[8];
            float s = 0.f, sq = 0.f;
            #pragma unroll
            for (int j = 0; j < 8; ++j) {
                v[j] = acc[t][j][reg] + bsv[j];
                s += v[j];
                sq += v[j] * v[j];
            }
            #pragma unroll
            for (int mk = 1; mk < 16; mk <<= 1) {
                s  += __shfl_xor(s, mk, 64);
                sq += __shfl_xor(sq, mk, 64);
            }
            float mu = s * (1.f / DIM);
            float var = sq * (1.f / DIM) - mu * mu;
            float rs = rsqrtf(var + LN_EPS);
            int n = n0 + t * 16 + q * 4 + reg;
            if (n < N_NODES) {
                #pragma unroll
                for (int j = 0; j < 8; ++j)
                    out[(size_t)n * DIM + j * 16 + m] = (v[j] - mu) * rs * gv[j] + bv[j];
            }
        }
    }
}

// ---------------------------------------------------------------------------
extern "C" void kernel_launch(void* const* d_in, const int* in_sizes, int n_in,
                              void* d_out, int out_size, void* d_ws, size_t ws_size,
                              hipStream_t stream) {
    const float* H      = (const float*)d_in[0];
    const int*   ei     = (const int*)d_in[1];
    const float* P      = (const float*)d_in[2];
    const float* deter  = (const float*)d_in[3];
    const float* W1     = (const float*)d_in[4];
    const float* W2     = (const float*)d_in[5];
    const float* W3     = (const float*)d_in[6];
    const float* W4     = (const float*)d_in[7];
    const float* Wv     = (const float*)d_in[8];
    const float* Wout_w = (const float*)d_in[9];
    const float* Wout_b = (const float*)d_in[10];
    const float* res_w  = (const float*)d_in[11];
    const float* res_b  = (const float*)d_in[12];
    const float* ln_g   = (const float*)d_in[13];
    const float* ln_b   = (const float*)d_in[14];

    float* ws = (float*)d_ws;
    const size_t NH8 = (size_t)N_NODES * NHEADS;   // 400,000

    // ---- workspace layout (subset of the known-good baseline footprint) ----
    __half* Xh  = (__half*)ws;                       // N*256 halves = N*128 words
    float* fbase = ws + (size_t)N_NODES * 128;
    __half* Vh  = (__half*)fbase;                    // N*128 halves = N*64 words
    float* A1   = fbase + (size_t)N_NODES * 64;      // NH8
    float* A2   = A1 + NH8;                          // NH8
    float* cvec = A2 + NH8;                          // 16
    float* bsum = cvec + 16;                         // 128
    __half* Wch  = (__half*)(bsum + 128);            // 128*256 halves = 16384 words
    __half* Wcat = Wch + 128 * 256;                  // 144*128 halves = 9216 words
    // total < baseline's ~12.2M words (~49 MB)

    // ---- scratch in d_out (25.6 MB), 16B-aligned first:
    //   rec_tmp 6.4 MB + cnt 0.5 + ofs 0.5 + binTot 2 KB ≈ 7.4 MB.
    //   d_out is fully overwritten by k_out_mfma at the end.
    int2* rec_tmp = (int2*)d_out;                    // E * 8 B
    int* cnt     = (int*)(rec_tmp + N_EDGES);        // NCHUNK*NBINS ints
    int* ofs     = cnt + NCHUNK * NBINS;             // NCHUNK*NBINS ints
    int* binTot  = ofs + NCHUNK * NBINS;             // NBINS

    k_init<<<136 + NCHUNK, 256, 0, stream>>>(W1, W2, W3, W4, Wout_w, res_w, Wv,
                                             Wout_b, res_b, ei, Wch, Wcat,
                                             bsum, cvec, cnt);
    k_node_mfma<<<(N_NODES + 31) / 32, 64, 0, stream>>>(H, Wcat, Vh, Xh, A1, A2);
    k_scanchunk<<<NBINS, NCHUNK, 0, stream>>>(cnt, ofs, binTot);
    k_place<<<NCHUNK, 256, 0, stream>>>(ei, P, deter, ofs, binTot, rec_tmp);
    k_rebin_agg<<<NBINS, 512, 0, stream>>>(binTot, rec_tmp, A1, A2, cvec,
                                           (const __half2*)Vh, Xh);
    k_out_mfma<<<(N_NODES + 31) / 32, 64, 0, stream>>>(Xh, Wch, bsum, ln_g, ln_b,
                                                       (float*)d_out);
}

// Round 9
// 220.216 us; speedup vs baseline: 1.0273x; 1.0273x over previous
//
#include <hip/hip_runtime.h>
#include <hip/hip_fp16.h>
#include <math.h>

#define N_NODES 50000
#define N_EDGES 800000
#define DIM 128
#define NHEADS 8
#define LN_EPS 1e-5f
#define LEAKY 0.2f
#define NBINS 1024
#define NPB 49     // nodes per bin; 1024*49 = 50176 >= N_NODES
#define NCHUNK 256 // edge chunks for counting sort
#define EPC 3125   // edges per chunk; 256*3125 = 800000 exactly
#define CAP 1280   // max edges per bin in LDS (mean 781, sigma ~28)

typedef _Float16 half8 __attribute__((ext_vector_type(8)));
typedef float floatx4 __attribute__((ext_vector_type(4)));

// ---------------- pack/unpack (P, deter) as half2 in one int ----------------
__device__ __forceinline__ int pack_pd(float p, float dt) {
    __half2 h = __floats2half2_rn(p, dt);
    int r; __builtin_memcpy(&r, &h, 4); return r;
}
__device__ __forceinline__ float2 unpack_pd(int v) {
    __half2 h; __builtin_memcpy(&h, &v, 4);
    return __half22float2(h);   // .x = P, .y = deter
}

// -- K1 (fused): blocks 0..127 -> Wch/Wcat[0:128]/bsum; 128..135 -> attn rows;
//    blocks 136..391 -> per-chunk per-bin histograms (counting sort phase 1).
__global__ __launch_bounds__(256) void k_init(
    const float* __restrict__ W1, const float* __restrict__ W2,
    const float* __restrict__ W3, const float* __restrict__ W4,
    const float* __restrict__ Wout, const float* __restrict__ Wres,
    const float* __restrict__ Wv, const float* __restrict__ bout,
    const float* __restrict__ bres, const int* __restrict__ ei,
    __half* __restrict__ Wch, __half* __restrict__ Wcat,
    float* __restrict__ bsum, float* __restrict__ c,
    int* __restrict__ cnt) {
    __shared__ float red[DIM];
    __shared__ int hh[NBINS];
    int b = blockIdx.x;
    int t = threadIdx.x;
    if (b < 128) {
        int d = b;
        float v = (t < 128) ? Wout[d * 128 + t] : Wres[d * 128 + (t - 128)];
        Wch[(size_t)d * 256 + t] = __float2half_rn(v);
        if (t < 128) Wcat[(size_t)d * DIM + t] = __float2half_rn(Wv[d * 128 + t]);
        if (d == 0 && t < 128) bsum[t] = bout[t] + bres[t];
    } else if (b < 136) {
        int h = b - 128;          // 0..7
        if (t < 128) {
            int k = t;
            float a1 = 0.f, a2 = 0.f;
            for (int d = 0; d < DIM; ++d) {
                float w4 = W4[h * DIM + d];
                a1 += w4 * W1[d * DIM + k];
                a2 += w4 * W2[d * DIM + k];
            }
            Wcat[(size_t)(128 + h) * DIM + k] = __float2half_rn(a1);
            Wcat[(size_t)(136 + h) * DIM + k] = __float2half_rn(a2);
        }
        if (t < 128) red[t] = W4[h * DIM + t] * W3[t];
        __syncthreads();
        if (t == 0) {
            float s = 0.f;
            for (int i = 0; i < DIM; ++i) s += red[i];
            c[h] = s;
        }
    } else {
        int ch = b - 136;         // chunk 0..255
        for (int i = t; i < NBINS; i += 256) hh[i] = 0;
        __syncthreads();
        int e0 = ch * EPC;
        for (int i = t; i < EPC; i += 256) {
            int dst = ei[N_EDGES + e0 + i];
            atomicAdd(&hh[dst / NPB], 1);      // LDS atomic — block-local
        }
        __syncthreads();
        // layout [chunk][bin] so k_place's reload is coalesced
        for (int i = t; i < NBINS; i += 256)
            cnt[(size_t)ch * NBINS + i] = hh[i];
    }
}

// -- K2: MFMA  Y = H @ Wcat^T  (M=N_NODES, N=144, K=128, fp16 in / fp32 acc) -
//   cols 0..127 -> Vh (fp16), cols 128..135 -> A1, 136..143 -> A2 (fp32)
//   side effect: Xh[:,128:256] = fp16(H)  (converted A-fragments)
__global__ __launch_bounds__(64) void k_node_mfma(
    const float* __restrict__ H, const __half* __restrict__ Wcat_,
    __half* __restrict__ Vh, __half* __restrict__ Xh,
    float* __restrict__ A1, float* __restrict__ A2) {
    const _Float16* Wcat = reinterpret_cast<const _Float16*>(Wcat_);
    int lane = threadIdx.x;          // 0..63
    int m = lane & 15, q = lane >> 4;
    int n0 = blockIdx.x * 32;
    floatx4 z = {0.f, 0.f, 0.f, 0.f};
    floatx4 acc[2][9];
    #pragma unroll
    for (int t = 0; t < 2; ++t)
        #pragma unroll
        for (int j = 0; j < 9; ++j) acc[t][j] = z;
    int r0 = n0 + m;        if (r0 >= N_NODES) r0 = N_NODES - 1;
    int r1 = n0 + 16 + m;   if (r1 >= N_NODES) r1 = N_NODES - 1;
    const float* H0 = H + (size_t)r0 * DIM + q * 8;
    const float* H1 = H + (size_t)r1 * DIM + q * 8;
    _Float16* Xw0 = reinterpret_cast<_Float16*>(Xh) + (size_t)r0 * 256 + 128 + q * 8;
    _Float16* Xw1 = reinterpret_cast<_Float16*>(Xh) + (size_t)r1 * 256 + 128 + q * 8;
    const _Float16* Wb = Wcat + (size_t)m * DIM + q * 8;
    #pragma unroll
    for (int ks = 0; ks < 4; ++ks) {
        float4 fa = *reinterpret_cast<const float4*>(H0 + ks * 32);
        float4 fb = *reinterpret_cast<const float4*>(H0 + ks * 32 + 4);
        float4 ga = *reinterpret_cast<const float4*>(H1 + ks * 32);
        float4 gb = *reinterpret_cast<const float4*>(H1 + ks * 32 + 4);
        half8 a0, a1v;
        a0[0] = (_Float16)fa.x; a0[1] = (_Float16)fa.y;
        a0[2] = (_Float16)fa.z; a0[3] = (_Float16)fa.w;
        a0[4] = (_Float16)fb.x; a0[5] = (_Float16)fb.y;
        a0[6] = (_Float16)fb.z; a0[7] = (_Float16)fb.w;
        a1v[0] = (_Float16)ga.x; a1v[1] = (_Float16)ga.y;
        a1v[2] = (_Float16)ga.z; a1v[3] = (_Float16)ga.w;
        a1v[4] = (_Float16)gb.x; a1v[5] = (_Float16)gb.y;
        a1v[6] = (_Float16)gb.z; a1v[7] = (_Float16)gb.w;
        *reinterpret_cast<half8*>(Xw0 + ks * 32) = a0;
        *reinterpret_cast<half8*>(Xw1 + ks * 32) = a1v;
        #pragma unroll
        for (int j = 0; j < 9; ++j) {
            half8 b = *reinterpret_cast<const half8*>(Wb + (size_t)j * 16 * DIM + ks * 32);
            acc[0][j] = __builtin_amdgcn_mfma_f32_16x16x32_f16(a0, b, acc[0][j], 0, 0, 0);
            acc[1][j] = __builtin_amdgcn_mfma_f32_16x16x32_f16(a1v, b, acc[1][j], 0, 0, 0);
        }
    }
    // C/D layout: col = m, row = q*4 + reg (within 16-row tile)
    #pragma unroll
    for (int t = 0; t < 2; ++t) {
        #pragma unroll
        for (int reg = 0; reg < 4; ++reg) {
            int n = n0 + t * 16 + q * 4 + reg;
            if (n < N_NODES) {
                #pragma unroll
                for (int j = 0; j < 8; ++j)
                    Vh[(size_t)n * DIM + j * 16 + m] = __float2half_rn(acc[t][j][reg]);
                float av = acc[t][8][reg];
                if (m < 8) A1[(size_t)n * NHEADS + m] = av;
                else       A2[(size_t)n * NHEADS + (m - 8)] = av;
            }
        }
    }
}

// ---------------- K5b: per-bin scan over chunks (relative); bin totals ------
__global__ __launch_bounds__(NCHUNK) void k_scanchunk(
    const int* __restrict__ cnt, int* __restrict__ ofs,
    int* __restrict__ binTot) {
    __shared__ int sh[NCHUNK];
    int b = blockIdx.x, t = threadIdx.x;
    int v = cnt[(size_t)t * NBINS + b];
    sh[t] = v;
    __syncthreads();
    #pragma unroll
    for (int off = 1; off < NCHUNK; off <<= 1) {
        int u = (t >= off) ? sh[t - off] : 0;
        __syncthreads();
        sh[t] += u;
        __syncthreads();
    }
    ofs[(size_t)t * NBINS + b] = sh[t] - v;   // chunk-exclusive, bin-relative
    if (t == NCHUNK - 1) binTot[b] = sh[t];
}

// ---------------- K5d: place records into bin regions (LDS cursors) --------
// In-block inclusive scan of binTot[1024] (4 elems/thread over 256 threads).
__global__ __launch_bounds__(256) void k_place(
    const int* __restrict__ ei, const float* __restrict__ P,
    const float* __restrict__ deter, const int* __restrict__ ofs,
    const int* __restrict__ binTot, int2* __restrict__ rec_tmp) {
    __shared__ int ps[256];
    __shared__ int cur[NBINS];
    int t = threadIdx.x;
    int v0 = binTot[4 * t],     v1 = binTot[4 * t + 1];
    int v2 = binTot[4 * t + 2], v3 = binTot[4 * t + 3];
    int s1 = v0 + v1, s2 = s1 + v2, s3 = s2 + v3;
    ps[t] = s3;
    __syncthreads();
    #pragma unroll
    for (int off = 1; off < 256; off <<= 1) {
        int u = (t >= off) ? ps[t - off] : 0;
        __syncthreads();
        ps[t] += u;
        __syncthreads();
    }
    int base = (t > 0) ? ps[t - 1] : 0;   // exclusive base of thread's 4 bins
    // cur[i] = chunk-relative ofs + exclusive bin base
    const int* o = ofs + (size_t)blockIdx.x * NBINS;
    cur[4 * t]     = o[4 * t]     + base;
    cur[4 * t + 1] = o[4 * t + 1] + base + v0;
    cur[4 * t + 2] = o[4 * t + 2] + base + s1;
    cur[4 * t + 3] = o[4 * t + 3] + base + s2;
    __syncthreads();
    int e0 = blockIdx.x * EPC;
    for (int i = t; i < EPC; i += 256) {
        int e = e0 + i;
        int src = ei[e];
        int dst = ei[N_EDGES + e];
        int pos = atomicAdd(&cur[dst / NPB], 1);   // LDS atomic
        rec_tmp[pos] = make_int2((dst << 16) | src, pack_pd(P[e], deter[e]));
    }
}

// ---- K5e (fused): per-bin CSR build + edge exp + aggregation, all in LDS ---
// 1024 bins -> 4 blocks/CU, 32 waves/CU; LDS ~23 KB so occupancy is
// grid/thread-limited, not LDS-limited. Own bin base via block reduction.
__global__ __launch_bounds__(512) void k_rebin_agg(
    const int* __restrict__ binTot, const int2* __restrict__ rec_tmp,
    const float* __restrict__ A1, const float* __restrict__ A2,
    const float* __restrict__ cvec, const __half2* __restrict__ Vh2,
    __half* __restrict__ Xh) {
    __shared__ int red8[8];
    __shared__ int cnt_l[NPB];   // exclusive global starts per node
    __shared__ int cur_l[NPB];   // atomic cursors -> node ends after scatter
    __shared__ float cs[NHEADS];
    __shared__ unsigned short wsrc[CAP];  // src per edge (bin-local order)
    __shared__ half8 wl[CAP];             // exp-weights per edge
    int b = blockIdx.x, t = threadIdx.x;
    int d = t & 63;
    int wv = t >> 6;             // wave 0..7
    int h = d >> 3;
    // inclusive sum binTot[0..b] via strided partial + block reduce
    int partial = 0;
    for (int i = t; i <= b; i += 512) partial += binTot[i];
    #pragma unroll
    for (int off = 32; off > 0; off >>= 1) partial += __shfl_down(partial, off, 64);
    if (d == 0) red8[wv] = partial;
    if (t < NHEADS) cs[t] = cvec[t];
    __syncthreads();
    int e = red8[0] + red8[1] + red8[2] + red8[3] +
            red8[4] + red8[5] + red8[6] + red8[7];   // end of bin b
    int s = e - binTot[b];                            // start of bin b
    int n0 = b * NPB;
    int nEdge = e - s;
    if (nEdge <= CAP) {
        for (int i = t; i < NPB; i += 512) cnt_l[i] = 0;
        __syncthreads();
        for (int i = s + t; i < e; i += 512) {
            int dst = ((unsigned)rec_tmp[i].x) >> 16;
            atomicAdd(&cnt_l[dst - n0], 1);
        }
        __syncthreads();
        if (t == 0) {   // tiny serial scan over 49 entries
            int acc = s;
            for (int i = 0; i < NPB; ++i) {
                int c = cnt_l[i];
                cnt_l[i] = acc;
                cur_l[i] = acc;
                acc += c;
            }
        }
        __syncthreads();
        // scatter into LDS + fused exp(leaky(logit) - 4)
        for (int i = s + t; i < e; i += 512) {
            int2 r = rec_tmp[i];
            int dst = ((unsigned)r.x) >> 16;
            int src = r.x & 0xFFFF;
            float2 pd = unpack_pd(r.y);
            int pos = atomicAdd(&cur_l[dst - n0], 1);   // LDS atomic
            int li = pos - s;
            wsrc[li] = (unsigned short)src;
            float4 a1lo = *reinterpret_cast<const float4*>(A1 + (size_t)dst * NHEADS);
            float4 a1hi = *reinterpret_cast<const float4*>(A1 + (size_t)dst * NHEADS + 4);
            float4 a2lo = *reinterpret_cast<const float4*>(A2 + (size_t)src * NHEADS);
            float4 a2hi = *reinterpret_cast<const float4*>(A2 + (size_t)src * NHEADS + 4);
            float a1v[8] = {a1lo.x, a1lo.y, a1lo.z, a1lo.w, a1hi.x, a1hi.y, a1hi.z, a1hi.w};
            float a2v[8] = {a2lo.x, a2lo.y, a2lo.z, a2lo.w, a2hi.x, a2hi.y, a2hi.z, a2hi.w};
            half8 o;
            #pragma unroll
            for (int hh = 0; hh < NHEADS; ++hh) {
                float l = a1v[hh] + a2v[hh] + pd.x * cs[hh] + pd.y;
                l = (l >= 0.f) ? l : LEAKY * l;
                o[hh] = (_Float16)__expf(l - 4.0f);
            }
            wl[li] = o;
        }
        __syncthreads();
        // aggregation: wave wv handles nodes wv, wv+8, ... of this bin
        for (int ni = wv; ni < NPB; ni += 8) {
            int n = n0 + ni;
            if (n >= N_NODES) break;
            int st = cnt_l[ni] - s;
            int en = cur_l[ni] - s;
            float sum = 0.f, ax = 0.f, ay = 0.f;
            int j = st;
            for (; j + 8 <= en; j += 8) {
                int sv[8];
                float wv8[8];
                __half2 vv[8];
                #pragma unroll
                for (int k = 0; k < 8; ++k) sv[k] = wsrc[j + k];
                #pragma unroll
                for (int k = 0; k < 8; ++k) wv8[k] = (float)wl[j + k][h];
                #pragma unroll
                for (int k = 0; k < 8; ++k) vv[k] = Vh2[(size_t)sv[k] * (DIM / 2) + d];
                #pragma unroll
                for (int k = 0; k < 8; ++k) {
                    sum += wv8[k];
                    float2 f = __half22float2(vv[k]);
                    ax += wv8[k] * f.x;
                    ay += wv8[k] * f.y;
                }
            }
            for (; j < en; ++j) {
                int src = wsrc[j];
                float wvv = (float)wl[j][h];
                sum += wvv;
                float2 vf = __half22float2(Vh2[(size_t)src * (DIM / 2) + d]);
                ax += wvv * vf.x;
                ay += wvv * vf.y;
            }
            float inv = 1.f / (sum + 1e-12f);
            __half2 o = __floats2half2_rn(ax * inv, ay * inv);
            *reinterpret_cast<__half2*>(Xh + (size_t)n * 256 + 2 * d) = o;
        }
    } else {
        // robust fallback (block-uniform branch; statistically never taken):
        // direct filter-aggregate from global rec_tmp, exp recomputed per lane
        __syncthreads();
        for (int ni = wv; ni < NPB; ni += 8) {
            int n = n0 + ni;
            if (n >= N_NODES) break;
            float a1 = A1[(size_t)n * NHEADS + h];
            float sum = 0.f, ax = 0.f, ay = 0.f;
            for (int i = s; i < e; ++i) {
                int2 r = rec_tmp[i];
                int dst = ((unsigned)r.x) >> 16;
                if (dst != n) continue;
                int src = r.x & 0xFFFF;
                float2 pd = unpack_pd(r.y);
                float a2 = A2[(size_t)src * NHEADS + h];
                float l = a1 + a2 + pd.x * cs[h] + pd.y;
                l = (l >= 0.f) ? l : LEAKY * l;
                float ev = __expf(l - 4.0f);
                sum += ev;
                float2 vf = __half22float2(Vh2[(size_t)src * (DIM / 2) + d]);
                ax += ev * vf.x;
                ay += ev * vf.y;
            }
            float inv = 1.f / (sum + 1e-12f);
            __half2 o = __floats2half2_rn(ax * inv, ay * inv);
            *reinterpret_cast<__half2*>(Xh + (size_t)n * 256 + 2 * d) = o;
        }
    }
}

// -- K7: out = Xh(N,256) @ Wch(128,256)^T + bsum, LayerNorm — MFMA -----------
__global__ __launch_bounds__(64) void k_out_mfma(
    const __half* __restrict__ Xh_, const __half* __restrict__ Wch_,
    const float* __restrict__ bsum, const float* __restrict__ ln_g,
    const float* __restrict__ ln_b, float* __restrict__ out) {
    const _Float16* Xh = reinterpret_cast<const _Float16*>(Xh_);
    const _Float16* Wch = reinterpret_cast<const _Float16*>(Wch_);
    int lane = threadIdx.x;          // 0..63
    int m = lane & 15, q = lane >> 4;
    int n0 = blockIdx.x * 32;
    floatx4 z = {0.f, 0.f, 0.f, 0.f};
    floatx4 acc[2][8];
    #pragma unroll
    for (int t = 0; t < 2; ++t)
        #pragma unroll
        for (int j = 0; j < 8; ++j) acc[t][j] = z;
    int r0 = n0 + m;        if (r0 >= N_NODES) r0 = N_NODES - 1;
    int r1 = n0 + 16 + m;   if (r1 >= N_NODES) r1 = N_NODES - 1;
    const _Float16* X0 = Xh + (size_t)r0 * 256 + q * 8;
    const _Float16* X1 = Xh + (size_t)r1 * 256 + q * 8;
    const _Float16* Wb = Wch + (size_t)m * 256 + q * 8;
    #pragma unroll
    for (int ks = 0; ks < 8; ++ks) {
        half8 a0 = *reinterpret_cast<const half8*>(X0 + ks * 32);
        half8 a1 = *reinterpret_cast<const half8*>(X1 + ks * 32);
        #pragma unroll
        for (int j = 0; j < 8; ++j) {
            half8 b = *reinterpret_cast<const half8*>(Wb + (size_t)j * 16 * 256 + ks * 32);
            acc[0][j] = __builtin_amdgcn_mfma_f32_16x16x32_f16(a0, b, acc[0][j], 0, 0, 0);
            acc[1][j] = __builtin_amdgcn_mfma_f32_16x16x32_f16(a1, b, acc[1][j], 0, 0, 0);
        }
    }
    float bsv[8], gv[8], bv[8];
    #pragma unroll
    for (int j = 0; j < 8; ++j) {
        bsv[j] = bsum[j * 16 + m];
        gv[j]  = ln_g[j * 16 + m];
        bv[j]  = ln_b[j * 16 + m];
    }
    #pragma unroll
    for (int t = 0; t < 2; ++t) {
        #pragma unroll
        for (int reg = 0; reg < 4; ++reg) {
            float v[8];
            float s = 0.f, sq = 0.f;
            #pragma unroll
            for (int j = 0; j < 8; ++j) {
                v[j] = acc[t][j][reg] + bsv[j];
                s += v[j];
                sq += v[j] * v[j];
            }
            #pragma unroll
            for (int mk = 1; mk < 16; mk <<= 1) {
                s  += __shfl_xor(s, mk, 64);
                sq += __shfl_xor(sq, mk, 64);
            }
            float mu = s * (1.f / DIM);
            float var = sq * (1.f / DIM) - mu * mu;
            float rs = rsqrtf(var + LN_EPS);
            int n = n0 + t * 16 + q * 4 + reg;
            if (n < N_NODES) {
                #pragma unroll
                for (int j = 0; j < 8; ++j)
                    out[(size_t)n * DIM + j * 16 + m] = (v[j] - mu) * rs * gv[j] + bv[j];
            }
        }
    }
}

// ---------------------------------------------------------------------------
extern "C" void kernel_launch(void* const* d_in, const int* in_sizes, int n_in,
                              void* d_out, int out_size, void* d_ws, size_t ws_size,
                              hipStream_t stream) {
    const float* H      = (const float*)d_in[0];
    const int*   ei     = (const int*)d_in[1];
    const float* P      = (const float*)d_in[2];
    const float* deter  = (const float*)d_in[3];
    const float* W1     = (const float*)d_in[4];
    const float* W2     = (const float*)d_in[5];
    const float* W3     = (const float*)d_in[6];
    const float* W4     = (const float*)d_in[7];
    const float* Wv     = (const float*)d_in[8];
    const float* Wout_w = (const float*)d_in[9];
    const float* Wout_b = (const float*)d_in[10];
    const float* res_w  = (const float*)d_in[11];
    const float* res_b  = (const float*)d_in[12];
    const float* ln_g   = (const float*)d_in[13];
    const float* ln_b   = (const float*)d_in[14];

    float* ws = (float*)d_ws;
    const size_t NH8 = (size_t)N_NODES * NHEADS;   // 400,000

    // ---- workspace layout (subset of the known-good baseline footprint) ----
    __half* Xh  = (__half*)ws;                       // N*256 halves = N*128 words
    float* fbase = ws + (size_t)N_NODES * 128;
    __half* Vh  = (__half*)fbase;                    // N*128 halves = N*64 words
    float* A1   = fbase + (size_t)N_NODES * 64;      // NH8
    float* A2   = A1 + NH8;                          // NH8
    float* cvec = A2 + NH8;                          // 16
    float* bsum = cvec + 16;                         // 128
    __half* Wch  = (__half*)(bsum + 128);            // 128*256 halves = 16384 words
    __half* Wcat = Wch + 128 * 256;                  // 144*128 halves = 9216 words
    // total < baseline's ~12.2M words (~49 MB)

    // ---- scratch in d_out (25.6 MB), 16B-aligned first:
    //   rec_tmp 6.4 MB + cnt 1 MB + ofs 1 MB + binTot 4 KB ≈ 8.4 MB.
    //   d_out is fully overwritten by k_out_mfma at the end.
    int2* rec_tmp = (int2*)d_out;                    // E * 8 B
    int* cnt     = (int*)(rec_tmp + N_EDGES);        // NCHUNK*NBINS ints
    int* ofs     = cnt + NCHUNK * NBINS;             // NCHUNK*NBINS ints
    int* binTot  = ofs + NCHUNK * NBINS;             // NBINS

    k_init<<<136 + NCHUNK, 256, 0, stream>>>(W1, W2, W3, W4, Wout_w, res_w, Wv,
                                             Wout_b, res_b, ei, Wch, Wcat,
                                             bsum, cvec, cnt);
    k_node_mfma<<<(N_NODES + 31) / 32, 64, 0, stream>>>(H, Wcat, Vh, Xh, A1, A2);
    k_scanchunk<<<NBINS, NCHUNK, 0, stream>>>(cnt, ofs, binTot);
    k_place<<<NCHUNK, 256, 0, stream>>>(ei, P, deter, ofs, binTot, rec_tmp);
    k_rebin_agg<<<NBINS, 512, 0, stream>>>(binTot, rec_tmp, A1, A2, cvec,
                                           (const __half2*)Vh, Xh);
    k_out_mfma<<<(N_NODES + 31) / 32, 64, 0, stream>>>(Xh, Wch, bsum, ln_g, ln_b,
                                                       (float*)d_out);
}

// Round 10
// 212.296 us; speedup vs baseline: 1.0657x; 1.0373x over previous
//
#include <hip/hip_runtime.h>
#include <hip/hip_fp16.h>
#include <math.h>

#define N_NODES 50000
#define N_EDGES 800000
#define DIM 128
#define NHEADS 8
#define LN_EPS 1e-5f
#define LEAKY 0.2f
#define NBINS 2048
#define NPB 25     // nodes per bin; 2048*25 = 51200 >= N_NODES
#define NCHUNK 256 // edge chunks for counting sort
#define EPC 3125   // edges per chunk; 256*3125 = 800000 exactly
#define CAP 640    // max edges per bin in LDS (mean 391, sigma ~20)
#define CAPP 644   // plane stride in words; 644%32=4 -> head planes hit
                   // banks {0,4,...,28}: conflict-free group-broadcast reads

typedef _Float16 half8 __attribute__((ext_vector_type(8)));
typedef float floatx4 __attribute__((ext_vector_type(4)));

// ---------------- pack/unpack (P, deter) as half2 in one int ----------------
__device__ __forceinline__ int pack_pd(float p, float dt) {
    __half2 h = __floats2half2_rn(p, dt);
    int r; __builtin_memcpy(&r, &h, 4); return r;
}
__device__ __forceinline__ float2 unpack_pd(int v) {
    __half2 h; __builtin_memcpy(&h, &v, 4);
    return __half22float2(h);   // .x = P, .y = deter
}

// -- K1 (fused): blocks 0..127 -> Wch/Wcat[0:128]/bsum; 128..135 -> attn rows;
//    blocks 136..391 -> per-chunk per-bin histograms (counting sort phase 1).
__global__ __launch_bounds__(256) void k_init(
    const float* __restrict__ W1, const float* __restrict__ W2,
    const float* __restrict__ W3, const float* __restrict__ W4,
    const float* __restrict__ Wout, const float* __restrict__ Wres,
    const float* __restrict__ Wv, const float* __restrict__ bout,
    const float* __restrict__ bres, const int* __restrict__ ei,
    __half* __restrict__ Wch, __half* __restrict__ Wcat,
    float* __restrict__ bsum, float* __restrict__ c,
    int* __restrict__ cnt) {
    __shared__ float red[DIM];
    __shared__ int hh[NBINS];
    int b = blockIdx.x;
    int t = threadIdx.x;
    if (b < 128) {
        int d = b;
        float v = (t < 128) ? Wout[d * 128 + t] : Wres[d * 128 + (t - 128)];
        Wch[(size_t)d * 256 + t] = __float2half_rn(v);
        if (t < 128) Wcat[(size_t)d * DIM + t] = __float2half_rn(Wv[d * 128 + t]);
        if (d == 0 && t < 128) bsum[t] = bout[t] + bres[t];
    } else if (b < 136) {
        int h = b - 128;          // 0..7
        if (t < 128) {
            int k = t;
            float a1 = 0.f, a2 = 0.f;
            for (int d = 0; d < DIM; ++d) {
                float w4 = W4[h * DIM + d];
                a1 += w4 * W1[d * DIM + k];
                a2 += w4 * W2[d * DIM + k];
            }
            Wcat[(size_t)(128 + h) * DIM + k] = __float2half_rn(a1);
            Wcat[(size_t)(136 + h) * DIM + k] = __float2half_rn(a2);
        }
        if (t < 128) red[t] = W4[h * DIM + t] * W3[t];
        __syncthreads();
        if (t == 0) {
            float s = 0.f;
            for (int i = 0; i < DIM; ++i) s += red[i];
            c[h] = s;
        }
    } else {
        int ch = b - 136;         // chunk 0..255
        for (int i = t; i < NBINS; i += 256) hh[i] = 0;
        __syncthreads();
        int e0 = ch * EPC;
        for (int i = t; i < EPC; i += 256) {
            int dst = ei[N_EDGES + e0 + i];
            atomicAdd(&hh[dst / NPB], 1);      // LDS atomic — block-local
        }
        __syncthreads();
        // layout [chunk][bin] so k_place's reload is coalesced
        for (int i = t; i < NBINS; i += 256)
            cnt[(size_t)ch * NBINS + i] = hh[i];
    }
}

// -- K2: MFMA  Y = H @ Wcat^T  (M=N_NODES, N=144, K=128, fp16 in / fp32 acc) -
//   cols 0..127 -> Vh (fp16), cols 128..135 -> A1, 136..143 -> A2 (fp32)
//   side effect: Xh[:,128:256] = fp16(H)  (converted A-fragments)
__global__ __launch_bounds__(64) void k_node_mfma(
    const float* __restrict__ H, const __half* __restrict__ Wcat_,
    __half* __restrict__ Vh, __half* __restrict__ Xh,
    float* __restrict__ A1, float* __restrict__ A2) {
    const _Float16* Wcat = reinterpret_cast<const _Float16*>(Wcat_);
    int lane = threadIdx.x;          // 0..63
    int m = lane & 15, q = lane >> 4;
    int n0 = blockIdx.x * 32;
    floatx4 z = {0.f, 0.f, 0.f, 0.f};
    floatx4 acc[2][9];
    #pragma unroll
    for (int t = 0; t < 2; ++t)
        #pragma unroll
        for (int j = 0; j < 9; ++j) acc[t][j] = z;
    int r0 = n0 + m;        if (r0 >= N_NODES) r0 = N_NODES - 1;
    int r1 = n0 + 16 + m;   if (r1 >= N_NODES) r1 = N_NODES - 1;
    const float* H0 = H + (size_t)r0 * DIM + q * 8;
    const float* H1 = H + (size_t)r1 * DIM + q * 8;
    _Float16* Xw0 = reinterpret_cast<_Float16*>(Xh) + (size_t)r0 * 256 + 128 + q * 8;
    _Float16* Xw1 = reinterpret_cast<_Float16*>(Xh) + (size_t)r1 * 256 + 128 + q * 8;
    const _Float16* Wb = Wcat + (size_t)m * DIM + q * 8;
    #pragma unroll
    for (int ks = 0; ks < 4; ++ks) {
        float4 fa = *reinterpret_cast<const float4*>(H0 + ks * 32);
        float4 fb = *reinterpret_cast<const float4*>(H0 + ks * 32 + 4);
        float4 ga = *reinterpret_cast<const float4*>(H1 + ks * 32);
        float4 gb = *reinterpret_cast<const float4*>(H1 + ks * 32 + 4);
        half8 a0, a1v;
        a0[0] = (_Float16)fa.x; a0[1] = (_Float16)fa.y;
        a0[2] = (_Float16)fa.z; a0[3] = (_Float16)fa.w;
        a0[4] = (_Float16)fb.x; a0[5] = (_Float16)fb.y;
        a0[6] = (_Float16)fb.z; a0[7] = (_Float16)fb.w;
        a1v[0] = (_Float16)ga.x; a1v[1] = (_Float16)ga.y;
        a1v[2] = (_Float16)ga.z; a1v[3] = (_Float16)ga.w;
        a1v[4] = (_Float16)gb.x; a1v[5] = (_Float16)gb.y;
        a1v[6] = (_Float16)gb.z; a1v[7] = (_Float16)gb.w;
        *reinterpret_cast<half8*>(Xw0 + ks * 32) = a0;
        *reinterpret_cast<half8*>(Xw1 + ks * 32) = a1v;
        #pragma unroll
        for (int j = 0; j < 9; ++j) {
            half8 b = *reinterpret_cast<const half8*>(Wb + (size_t)j * 16 * DIM + ks * 32);
            acc[0][j] = __builtin_amdgcn_mfma_f32_16x16x32_f16(a0, b, acc[0][j], 0, 0, 0);
            acc[1][j] = __builtin_amdgcn_mfma_f32_16x16x32_f16(a1v, b, acc[1][j], 0, 0, 0);
        }
    }
    // C/D layout: col = m, row = q*4 + reg (within 16-row tile)
    #pragma unroll
    for (int t = 0; t < 2; ++t) {
        #pragma unroll
        for (int reg = 0; reg < 4; ++reg) {
            int n = n0 + t * 16 + q * 4 + reg;
            if (n < N_NODES) {
                #pragma unroll
                for (int j = 0; j < 8; ++j)
                    Vh[(size_t)n * DIM + j * 16 + m] = __float2half_rn(acc[t][j][reg]);
                float av = acc[t][8][reg];
                if (m < 8) A1[(size_t)n * NHEADS + m] = av;
                else       A2[(size_t)n * NHEADS + (m - 8)] = av;
            }
        }
    }
}

// ---------------- K5b: per-bin scan over chunks (relative); bin totals ------
__global__ __launch_bounds__(NCHUNK) void k_scanchunk(
    const int* __restrict__ cnt, int* __restrict__ ofs,
    int* __restrict__ binTot) {
    __shared__ int sh[NCHUNK];
    int b = blockIdx.x, t = threadIdx.x;
    int v = cnt[(size_t)t * NBINS + b];
    sh[t] = v;
    __syncthreads();
    #pragma unroll
    for (int off = 1; off < NCHUNK; off <<= 1) {
        int u = (t >= off) ? sh[t - off] : 0;
        __syncthreads();
        sh[t] += u;
        __syncthreads();
    }
    ofs[(size_t)t * NBINS + b] = sh[t] - v;   // chunk-exclusive, bin-relative
    if (t == NCHUNK - 1) binTot[b] = sh[t];
}

// ---------------- K5d: place records into bin regions (LDS cursors) --------
// In-block inclusive scan of binTot[2048] (8 elems/thread over 256 threads).
__global__ __launch_bounds__(256) void k_place(
    const int* __restrict__ ei, const float* __restrict__ P,
    const float* __restrict__ deter, const int* __restrict__ ofs,
    const int* __restrict__ binTot, int2* __restrict__ rec_tmp) {
    __shared__ int ps[256];
    __shared__ int cur[NBINS];
    int t = threadIdx.x;
    int v[8];
    int run = 0;
    #pragma unroll
    for (int k = 0; k < 8; ++k) { v[k] = binTot[8 * t + k]; run += v[k]; }
    ps[t] = run;
    __syncthreads();
    #pragma unroll
    for (int off = 1; off < 256; off <<= 1) {
        int u = (t >= off) ? ps[t - off] : 0;
        __syncthreads();
        ps[t] += u;
        __syncthreads();
    }
    int acc = (t > 0) ? ps[t - 1] : 0;   // exclusive base of thread's 8 bins
    const int* o = ofs + (size_t)blockIdx.x * NBINS;
    #pragma unroll
    for (int k = 0; k < 8; ++k) {
        cur[8 * t + k] = o[8 * t + k] + acc;
        acc += v[k];
    }
    __syncthreads();
    int e0 = blockIdx.x * EPC;
    for (int i = t; i < EPC; i += 256) {
        int e = e0 + i;
        int src = ei[e];
        int dst = ei[N_EDGES + e];
        int pos = atomicAdd(&cur[dst / NPB], 1);   // LDS atomic
        rec_tmp[pos] = make_int2((dst << 16) | src, pack_pd(P[e], deter[e]));
    }
}

// ---- K5e (fused): per-bin CSR build + edge exp + aggregation, all in LDS ---
// Head-major LDS planes: whb[h][edge] = (src<<16) | fp16bits(w_h).
// Agg inner loop = ONE ds_read_b32 per edge; 8 head-groups hit 8 distinct
// banks (CAPP%32=4), 8 lanes broadcast each -> conflict-free.
__global__ __launch_bounds__(512) void k_rebin_agg(
    const int* __restrict__ binTot, const int2* __restrict__ rec_tmp,
    const float* __restrict__ A1, const float* __restrict__ A2,
    const float* __restrict__ cvec, const __half2* __restrict__ Vh2,
    __half* __restrict__ Xh) {
    __shared__ int red8[8];
    __shared__ int cnt_l[NPB];   // exclusive global starts per node
    __shared__ int cur_l[NPB];   // atomic cursors -> node ends after scatter
    __shared__ float cs[NHEADS];
    __shared__ int whb[NHEADS][CAPP];   // (src<<16)|halfbits(w) per head plane
    int b = blockIdx.x, t = threadIdx.x;
    int d = t & 63;
    int wv = t >> 6;             // wave 0..7
    int h = d >> 3;
    // inclusive sum binTot[0..b] via strided partial + block reduce
    int partial = 0;
    for (int i = t; i <= b; i += 512) partial += binTot[i];
    #pragma unroll
    for (int off = 32; off > 0; off >>= 1) partial += __shfl_down(partial, off, 64);
    if (d == 0) red8[wv] = partial;
    if (t < NHEADS) cs[t] = cvec[t];
    __syncthreads();
    int e = red8[0] + red8[1] + red8[2] + red8[3] +
            red8[4] + red8[5] + red8[6] + red8[7];   // end of bin b
    int s = e - binTot[b];                            // start of bin b
    int n0 = b * NPB;
    int nEdge = e - s;
    if (nEdge <= CAP) {
        for (int i = t; i < NPB; i += 512) cnt_l[i] = 0;
        __syncthreads();
        for (int i = s + t; i < e; i += 512) {
            int dst = ((unsigned)rec_tmp[i].x) >> 16;
            atomicAdd(&cnt_l[dst - n0], 1);
        }
        __syncthreads();
        if (t == 0) {   // tiny serial scan over 25 entries
            int acc = s;
            for (int i = 0; i < NPB; ++i) {
                int c = cnt_l[i];
                cnt_l[i] = acc;
                cur_l[i] = acc;
                acc += c;
            }
        }
        __syncthreads();
        // scatter into head-major LDS planes + fused exp(leaky(logit) - 4)
        for (int i = s + t; i < e; i += 512) {
            int2 r = rec_tmp[i];
            int dst = ((unsigned)r.x) >> 16;
            int src = r.x & 0xFFFF;
            float2 pd = unpack_pd(r.y);
            int pos = atomicAdd(&cur_l[dst - n0], 1);   // LDS atomic
            int li = pos - s;
            float4 a1lo = *reinterpret_cast<const float4*>(A1 + (size_t)dst * NHEADS);
            float4 a1hi = *reinterpret_cast<const float4*>(A1 + (size_t)dst * NHEADS + 4);
            float4 a2lo = *reinterpret_cast<const float4*>(A2 + (size_t)src * NHEADS);
            float4 a2hi = *reinterpret_cast<const float4*>(A2 + (size_t)src * NHEADS + 4);
            float a1v[8] = {a1lo.x, a1lo.y, a1lo.z, a1lo.w, a1hi.x, a1hi.y, a1hi.z, a1hi.w};
            float a2v[8] = {a2lo.x, a2lo.y, a2lo.z, a2lo.w, a2hi.x, a2hi.y, a2hi.z, a2hi.w};
            int sh16 = src << 16;
            #pragma unroll
            for (int hh = 0; hh < NHEADS; ++hh) {
                float l = a1v[hh] + a2v[hh] + pd.x * cs[hh] + pd.y;
                l = (l >= 0.f) ? l : LEAKY * l;
                _Float16 hv = (_Float16)__expf(l - 4.0f);
                unsigned short wb;
                __builtin_memcpy(&wb, &hv, 2);
                whb[hh][li] = sh16 | wb;
            }
        }
        __syncthreads();
        // aggregation: wave wv handles nodes wv, wv+8, ... of this bin
        for (int ni = wv; ni < NPB; ni += 8) {
            int n = n0 + ni;
            if (n >= N_NODES) break;
            int st = cnt_l[ni] - s;
            int en = cur_l[ni] - s;
            float sum = 0.f, ax = 0.f, ay = 0.f;
            int j = st;
            for (; j + 8 <= en; j += 8) {
                int rv[8];
                #pragma unroll
                for (int k = 0; k < 8; ++k) rv[k] = whb[h][j + k];
                int sv[8];
                float wv8[8];
                #pragma unroll
                for (int k = 0; k < 8; ++k) {
                    sv[k] = ((unsigned)rv[k]) >> 16;
                    unsigned short wb = (unsigned short)(rv[k] & 0xFFFF);
                    _Float16 hv;
                    __builtin_memcpy(&hv, &wb, 2);
                    wv8[k] = (float)hv;
                }
                __half2 vv[8];
                #pragma unroll
                for (int k = 0; k < 8; ++k) vv[k] = Vh2[(size_t)sv[k] * (DIM / 2) + d];
                #pragma unroll
                for (int k = 0; k < 8; ++k) {
                    sum += wv8[k];
                    float2 f = __half22float2(vv[k]);
                    ax += wv8[k] * f.x;
                    ay += wv8[k] * f.y;
                }
            }
            for (; j < en; ++j) {
                int rv = whb[h][j];
                int src = ((unsigned)rv) >> 16;
                unsigned short wb = (unsigned short)(rv & 0xFFFF);
                _Float16 hv;
                __builtin_memcpy(&hv, &wb, 2);
                float wvv = (float)hv;
                sum += wvv;
                float2 vf = __half22float2(Vh2[(size_t)src * (DIM / 2) + d]);
                ax += wvv * vf.x;
                ay += wvv * vf.y;
            }
            float inv = 1.f / (sum + 1e-12f);
            __half2 o = __floats2half2_rn(ax * inv, ay * inv);
            *reinterpret_cast<__half2*>(Xh + (size_t)n * 256 + 2 * d) = o;
        }
    } else {
        // robust fallback (block-uniform branch; statistically never taken):
        // direct filter-aggregate from global rec_tmp, exp recomputed per lane
        __syncthreads();
        for (int ni = wv; ni < NPB; ni += 8) {
            int n = n0 + ni;
            if (n >= N_NODES) break;
            float a1 = A1[(size_t)n * NHEADS + h];
            float sum = 0.f, ax = 0.f, ay = 0.f;
            for (int i = s; i < e; ++i) {
                int2 r = rec_tmp[i];
                int dst = ((unsigned)r.x) >> 16;
                if (dst != n) continue;
                int src = r.x & 0xFFFF;
                float2 pd = unpack_pd(r.y);
                float a2 = A2[(size_t)src * NHEADS + h];
                float l = a1 + a2 + pd.x * cs[h] + pd.y;
                l = (l >= 0.f) ? l : LEAKY * l;
                float ev = __expf(l - 4.0f);
                sum += ev;
                float2 vf = __half22float2(Vh2[(size_t)src * (DIM / 2) + d]);
                ax += ev * vf.x;
                ay += ev * vf.y;
            }
            float inv = 1.f / (sum + 1e-12f);
            __half2 o = __floats2half2_rn(ax * inv, ay * inv);
            *reinterpret_cast<__half2*>(Xh + (size_t)n * 256 + 2 * d) = o;
        }
    }
}

// -- K7: out = Xh(N,256) @ Wch(128,256)^T + bsum, LayerNorm — MFMA -----------
__global__ __launch_bounds__(64) void k_out_mfma(
    const __half* __restrict__ Xh_, const __half* __restrict__ Wch_,
    const float* __restrict__ bsum, const float* __restrict__ ln_g,
    const float* __restrict__ ln_b, float* __restrict__ out) {
    const _Float16* Xh = reinterpret_cast<const _Float16*>(Xh_);
    const _Float16* Wch = reinterpret_cast<const _Float16*>(Wch_);
    int lane = threadIdx.x;          // 0..63
    int m = lane & 15, q = lane >> 4;
    int n0 = blockIdx.x * 32;
    floatx4 z = {0.f, 0.f, 0.f, 0.f};
    floatx4 acc[2][8];
    #pragma unroll
    for (int t = 0; t < 2; ++t)
        #pragma unroll
        for (int j = 0; j < 8; ++j) acc[t][j] = z;
    int r0 = n0 + m;        if (r0 >= N_NODES) r0 = N_NODES - 1;
    int r1 = n0 + 16 + m;   if (r1 >= N_NODES) r1 = N_NODES - 1;
    const _Float16* X0 = Xh + (size_t)r0 * 256 + q * 8;
    const _Float16* X1 = Xh + (size_t)r1 * 256 + q * 8;
    const _Float16* Wb = Wch + (size_t)m * 256 + q * 8;
    #pragma unroll
    for (int ks = 0; ks < 8; ++ks) {
        half8 a0 = *reinterpret_cast<const half8*>(X0 + ks * 32);
        half8 a1 = *reinterpret_cast<const half8*>(X1 + ks * 32);
        #pragma unroll
        for (int j = 0; j < 8; ++j) {
            half8 b = *reinterpret_cast<const half8*>(Wb + (size_t)j * 16 * 256 + ks * 32);
            acc[0][j] = __builtin_amdgcn_mfma_f32_16x16x32_f16(a0, b, acc[0][j], 0, 0, 0);
            acc[1][j] = __builtin_amdgcn_mfma_f32_16x16x32_f16(a1, b, acc[1][j], 0, 0, 0);
        }
    }
    float bsv[8], gv[8], bv[8];
    #pragma unroll
    for (int j = 0; j < 8; ++j) {
        bsv[j] = bsum[j * 16 + m];
        gv[j]  = ln_g[j * 16 + m];
        bv[j]  = ln_b[j * 16 + m];
    }
    #pragma unroll
    for (int t = 0; t < 2; ++t) {
        #pragma unroll
        for (int reg = 0; reg < 4; ++reg) {
            float v[8];
            float s = 0.f, sq = 0.f;
            #pragma unroll
            for (int j = 0; j < 8; ++j) {
                v[j] = acc[t][j][reg] + bsv[j];
                s += v[j];
                sq += v[j] * v[j];
            }
            #pragma unroll
            for (int mk = 1; mk < 16; mk <<= 1) {
                s  += __shfl_xor(s, mk, 64);
                sq += __shfl_xor(sq, mk, 64);
            }
            float mu = s * (1.f / DIM);
            float var = sq * (1.f / DIM) - mu * mu;
            float rs = rsqrtf(var + LN_EPS);
            int n = n0 + t * 16 + q * 4 + reg;
            if (n < N_NODES) {
                #pragma unroll
                for (int j = 0; j < 8; ++j)
                    out[(size_t)n * DIM + j * 16 + m] = (v[j] - mu) * rs * gv[j] + bv[j];
            }
        }
    }
}

// ---------------------------------------------------------------------------
extern "C" void kernel_launch(void* const* d_in, const int* in_sizes, int n_in,
                              void* d_out, int out_size, void* d_ws, size_t ws_size,
                              hipStream_t stream) {
    const float* H      = (const float*)d_in[0];
    const int*   ei     = (const int*)d_in[1];
    const float* P      = (const float*)d_in[2];
    const float* deter  = (const float*)d_in[3];
    const float* W1     = (const float*)d_in[4];
    const float* W2     = (const float*)d_in[5];
    const float* W3     = (const float*)d_in[6];
    const float* W4     = (const float*)d_in[7];
    const float* Wv     = (const float*)d_in[8];
    const float* Wout_w = (const float*)d_in[9];
    const float* Wout_b = (const float*)d_in[10];
    const float* res_w  = (const float*)d_in[11];
    const float* res_b  = (const float*)d_in[12];
    const float* ln_g   = (const float*)d_in[13];
    const float* ln_b   = (const float*)d_in[14];

    float* ws = (float*)d_ws;
    const size_t NH8 = (size_t)N_NODES * NHEADS;   // 400,000

    // ---- workspace layout (subset of the known-good baseline footprint) ----
    __half* Xh  = (__half*)ws;                       // N*256 halves = N*128 words
    float* fbase = ws + (size_t)N_NODES * 128;
    __half* Vh  = (__half*)fbase;                    // N*128 halves = N*64 words
    float* A1   = fbase + (size_t)N_NODES * 64;      // NH8
    float* A2   = A1 + NH8;                          // NH8
    float* cvec = A2 + NH8;                          // 16
    float* bsum = cvec + 16;                         // 128
    __half* Wch  = (__half*)(bsum + 128);            // 128*256 halves = 16384 words
    __half* Wcat = Wch + 128 * 256;                  // 144*128 halves = 9216 words
    // total < baseline's ~12.2M words (~49 MB)

    // ---- scratch in d_out (25.6 MB), 16B-aligned first:
    //   rec_tmp 6.4 MB + cnt 2 MB + ofs 2 MB + binTot 8 KB ≈ 10.4 MB.
    //   d_out is fully overwritten by k_out_mfma at the end.
    int2* rec_tmp = (int2*)d_out;                    // E * 8 B
    int* cnt     = (int*)(rec_tmp + N_EDGES);        // NCHUNK*NBINS ints
    int* ofs     = cnt + NCHUNK * NBINS;             // NCHUNK*NBINS ints
    int* binTot  = ofs + NCHUNK * NBINS;             // NBINS

    k_init<<<136 + NCHUNK, 256, 0, stream>>>(W1, W2, W3, W4, Wout_w, res_w, Wv,
                                             Wout_b, res_b, ei, Wch, Wcat,
                                             bsum, cvec, cnt);
    k_node_mfma<<<(N_NODES + 31) / 32, 64, 0, stream>>>(H, Wcat, Vh, Xh, A1, A2);
    k_scanchunk<<<NBINS, NCHUNK, 0, stream>>>(cnt, ofs, binTot);
    k_place<<<NCHUNK, 256, 0, stream>>>(ei, P, deter, ofs, binTot, rec_tmp);
    k_rebin_agg<<<NBINS, 512, 0, stream>>>(binTot, rec_tmp, A1, A2, cvec,
                                           (const __half2*)Vh, Xh);
    k_out_mfma<<<(N_NODES + 31) / 32, 64, 0, stream>>>(Xh, Wch, bsum, ln_g, ln_b,
                                                       (float*)d_out);
}